// Round 7
// baseline (252.062 us; speedup 1.0000x reference)
//
#include <hip/hip_runtime.h>
#include <math.h>

#define NB 8            // batch
#define NPIX 262144     // 512*512
#define BPSAMP 64       // blocks per sample
#define NBLK (NB * BPSAMP)   // 512 blocks; capacity 1024 (4/CU via launch_bounds) => all co-resident, 2x margin
#define TPB 256
#define PPT 16          // pixels per thread (values live in registers)
#define PPB (TPB * PPT) // 4096 pixels per block
#define NBINS 1024      // level-1 bins: bits>>21 of a positive float is always < 1024
#define BPT (NBINS / TPB)    // 4 bins per thread in selection
#define NBINS2 256      // level-2 sub-bins: (bits>>13)&255
#define NGRP (NBLK / 64)     // 8 arrival groups (64 blocks each)
#define EPS2 1e-12f

#define F4E(v,j) (((const float*)&(v))[j])
#define I4E(v,j) (((const int*)&(v))[j])

struct Sel { unsigned b1, rem, k; };

__device__ __forceinline__ void pixel_vals(float a, float p,
                                           float i0, float i1, float i2,
                                           float f0, float f1, float f2,
                                           float g0, float g1, float g2,
                                           float& d, float& dc)
{
    float diff = a * (1.0f / 255.0f) - p;
    d = sqrtf(diff * diff + EPS2);
    float om = 1.0f - p;
    float e0 = i0 - (f0 * p + om * g0);
    float e1 = i1 - (f1 * p + om * g1);
    float e2 = i2 - (f2 * p + om * g2);
    dc = sqrtf(e0 * e0 + EPS2) + sqrtf(e1 * e1 + EPS2) + sqrtf(e2 * e2 + EPS2);
}

// Device-scope software grid barrier, contention-aware:
//  - arrival: two-level tree (8 group counters on separate 64B lines -> root line)
//  - wait: atomic LOAD poll on a dedicated flag line (no RMW thundering herd)
// Safe without cooperative launch: all NBLK=512 blocks co-resident by
// construction (4 blocks/CU cap from __launch_bounds__(256,4) => 1024 slots).
// Layout per slot (in unsigned words, slot stride 512 words = 2KB):
//   group g arrive counter at word g*16 (64B apart); root at word 128; flag at word 144.
__device__ void gridbar(unsigned* __restrict__ bar, int slot)
{
    __syncthreads();                       // all waves of this block done with prior phase
    if (threadIdx.x == 0) {
        __threadfence();                   // release: prior global writes device-visible
        unsigned* base = bar + slot * 512;
        const int g = blockIdx.x >> 6;     // 64 blocks per group
        unsigned a = __hip_atomic_fetch_add(base + g * 16, 1u,
                        __ATOMIC_ACQ_REL, __HIP_MEMORY_SCOPE_AGENT);
        if (a == 63u) {                    // last of group -> bump root
            unsigned r = __hip_atomic_fetch_add(base + 128, 1u,
                        __ATOMIC_ACQ_REL, __HIP_MEMORY_SCOPE_AGENT);
            if (r == (unsigned)(NGRP - 1)) // last group -> set flag
                __hip_atomic_store(base + 144, 1u,
                        __ATOMIC_RELEASE, __HIP_MEMORY_SCOPE_AGENT);
        }
        while (__hip_atomic_load(base + 144, __ATOMIC_ACQUIRE,
                        __HIP_MEMORY_SCOPE_AGENT) == 0u)
            __builtin_amdgcn_s_sleep(16);  // ~1K cycle backoff between load polls
        __threadfence();                   // acquire: subsequent plain loads see fresh data
    }
    __syncthreads();
}

// Block-collective selection over a 1024-bin count histogram: find b1 with
// count(bin > b1) < k <= count(bin >= b1); rem = k - count(bin > b1).
__device__ void select_unit(const unsigned* __restrict__ hc, unsigned k,
                            unsigned* sufB, unsigned* bcast, Sel& out)
{
    const int t = threadIdx.x;
    unsigned bins[BPT];
    unsigned pc = 0;
#pragma unroll
    for (int j = 0; j < BPT; ++j) { bins[j] = hc[t * BPT + j]; pc += bins[j]; }
    sufB[t] = pc;
    __syncthreads();
    // inclusive suffix sum (Hillis-Steele; read-sync-write-sync)
    for (int off = 1; off < TPB; off <<= 1) {
        unsigned add = (t + off < TPB) ? sufB[t + off] : 0u;
        __syncthreads();
        sufB[t] += add;
        __syncthreads();
    }
    unsigned suf = sufB[t];
    if (t == 0) { bcast[0] = 0xFFFFFFFFu; bcast[1] = 0u; bcast[2] = 0u; }
    __syncthreads();
    if (k > 0) {
        unsigned above = suf - pc;
        if (above < k && k <= suf) {       // exactly one thread
            unsigned c = above; int b1 = -1;
#pragma unroll
            for (int j = BPT - 1; j >= 0; --j) {
                if (b1 < 0) {
                    if (c + bins[j] >= k) b1 = t * BPT + j;
                    else c += bins[j];
                }
            }
            bcast[0] = (unsigned)b1; bcast[1] = k - c; bcast[2] = k;
        }
    }
    __syncthreads();
    out.b1 = bcast[0]; out.rem = bcast[1]; out.k = bcast[2];
    __syncthreads();   // safe LDS reuse after return
}

__global__ __launch_bounds__(TPB, 4) void k_fused(
    const float* __restrict__ image, const float* __restrict__ alpha,
    const float* __restrict__ pred, const int* __restrict__ trimap,
    const float* __restrict__ fg, const float* __restrict__ bg,
    unsigned* __restrict__ bar, unsigned* __restrict__ gcnt,
    unsigned* __restrict__ h1c, float* __restrict__ hpriv,
    float* __restrict__ sgl, float* __restrict__ out)
{
    __shared__ unsigned hc[2 * NBINS];     // 8KB  level-1 count hist (d, dc)
    __shared__ unsigned scnt[2 * NBINS2];  // 2KB  boundary sub-hist counts
    __shared__ float    ssum[2 * NBINS2];  // 2KB  boundary sub-hist sums
    __shared__ unsigned sufB[TPB];         // 1KB
    __shared__ float    sufF[TPB];         // 1KB
    __shared__ unsigned bcast[4];
    __shared__ float    fred[8];

    const int tid = threadIdx.x;
    const int b = blockIdx.x;
    const int s = b / BPSAMP;
    const int ch = b % BPSAMP;

    for (int i = tid; i < 2 * NBINS; i += TPB) hc[i] = 0u;
    for (int i = tid; i < 2 * NBINS2; i += TPB) { scnt[i] = 0u; ssum[i] = 0.f; }
    __syncthreads();

    // ---------------- Phase 1: stream inputs, values -> registers, LDS count hist ----------------
    const int pbase = s * NPIX + ch * PPB;
    const int cbase = s * 3 * NPIX + ch * PPB;
    float dv[PPT], cv[PPT];
    unsigned unkm = 0;
    unsigned nUnk = 0;

#pragma unroll
    for (int it = 0; it < PPT / 4; ++it) {
        const int off = (it * TPB + tid) * 4;
        int4   tm = *(const int4*)(trimap + pbase + off);
        float4 al = *(const float4*)(alpha + pbase + off);
        float4 pr = *(const float4*)(pred + pbase + off);
        float4 i0 = *(const float4*)(image + cbase + off);
        float4 i1 = *(const float4*)(image + cbase + NPIX + off);
        float4 i2 = *(const float4*)(image + cbase + 2 * NPIX + off);
        float4 f0 = *(const float4*)(fg + cbase + off);
        float4 f1 = *(const float4*)(fg + cbase + NPIX + off);
        float4 f2 = *(const float4*)(fg + cbase + 2 * NPIX + off);
        float4 g0 = *(const float4*)(bg + cbase + off);
        float4 g1 = *(const float4*)(bg + cbase + NPIX + off);
        float4 g2 = *(const float4*)(bg + cbase + 2 * NPIX + off);
#pragma unroll
        for (int j = 0; j < 4; ++j) {
            const int vi = it * 4 + j;
            float d = 0.f, c = 0.f;
            if (I4E(tm, j) == 128) {
                ++nUnk;
                unkm |= 1u << vi;
                pixel_vals(F4E(al, j), F4E(pr, j),
                           F4E(i0, j), F4E(i1, j), F4E(i2, j),
                           F4E(f0, j), F4E(f1, j), F4E(f2, j),
                           F4E(g0, j), F4E(g1, j), F4E(g2, j), d, c);
                atomicAdd(&hc[__float_as_uint(d) >> 21], 1u);           // plain LDS atomics
                atomicAdd(&hc[NBINS + (__float_as_uint(c) >> 21)], 1u); // (masked excluded: k < unknown count,
            }                                                            //  masked value = global min => same top-k sum)
            dv[vi] = d; cv[vi] = c;
        }
    }

    // per-sample unknown count
    unsigned u = nUnk;
#pragma unroll
    for (int o = 32; o > 0; o >>= 1) u += __shfl_down(u, o);
    if ((tid & 63) == 0) sufB[tid >> 6] = u;
    __syncthreads();
    if (tid == 0) atomicAdd(&gcnt[s], sufB[0] + sufB[1] + sufB[2] + sufB[3]);
    __syncthreads();

    // flush LDS hist -> global (only nonzero bins; device-scope atomics)
    for (int i = tid; i < 2 * NBINS; i += TPB) {
        unsigned cc = hc[i];
        if (cc) atomicAdd(&h1c[(s * 2 + (i >= NBINS ? 1 : 0)) * NBINS + (i & (NBINS - 1))], cc);
    }

    gridbar(bar, 0);

    // ---------------- Phase 2: per-block redundant selection for its sample's 2 units ----------------
    unsigned K = gcnt[s];
    unsigned kk = (unsigned)(int)floorf((float)K * 0.7f);
    Sel Sd, Sc;
    select_unit(h1c + (s * 2 + 0) * NBINS, kk, sufB, bcast, Sd);
    select_unit(h1c + (s * 2 + 1) * NBINS, kk, sufB, bcast, Sc);

    // ---------------- Phase 3: register re-scan: sum above b1 + boundary sub-hist ----------------
    float lsd = 0.f, lsc = 0.f;
#pragma unroll
    for (int vi = 0; vi < PPT; ++vi) {
        if (unkm & (1u << vi)) {
            unsigned bits = __float_as_uint(dv[vi]);
            unsigned bd = bits >> 21;
            if (Sd.b1 != 0xFFFFFFFFu) {
                if (bd > Sd.b1) lsd += dv[vi];
                else if (bd == Sd.b1) {
                    unsigned sb = (bits >> 13) & (NBINS2 - 1);
                    atomicAdd(&scnt[sb], 1u);
                    atomicAdd(&ssum[sb], dv[vi]);
                }
            }
            unsigned cbits = __float_as_uint(cv[vi]);
            unsigned bc = cbits >> 21;
            if (Sc.b1 != 0xFFFFFFFFu) {
                if (bc > Sc.b1) lsc += cv[vi];
                else if (bc == Sc.b1) {
                    unsigned sb = (cbits >> 13) & (NBINS2 - 1);
                    atomicAdd(&scnt[NBINS2 + sb], 1u);
                    atomicAdd(&ssum[NBINS2 + sb], cv[vi]);
                }
            }
        }
    }
#pragma unroll
    for (int o = 32; o > 0; o >>= 1) { lsd += __shfl_down(lsd, o); lsc += __shfl_down(lsc, o); }
    if ((tid & 63) == 0) { fred[tid >> 6] = lsd; fred[4 + (tid >> 6)] = lsc; }
    __syncthreads();   // also orders sub-hist LDS atomics before flush
    if (tid == 0) {
        sgl[(size_t)(s * BPSAMP + ch) * 2 + 0] = fred[0] + fred[1] + fred[2] + fred[3];
        sgl[(size_t)(s * BPSAMP + ch) * 2 + 1] = fred[4] + fred[5] + fred[6] + fred[7];
    }
    // private sub-hist store (plain stores; made visible by gridbar's release fence)
    {
        float* hp = hpriv + (size_t)(s * BPSAMP + ch) * (4 * NBINS2);
        hp[0 * NBINS2 + tid] = (float)scnt[tid];
        hp[1 * NBINS2 + tid] = ssum[tid];
        hp[2 * NBINS2 + tid] = (float)scnt[NBINS2 + tid];
        hp[3 * NBINS2 + tid] = ssum[NBINS2 + tid];
    }

    gridbar(bar, 1);

    // ---------------- Phase 4: 16 blocks finalize (block b = unit) ----------------
    if (b < 2 * NB) {
        const int uu = b, ss = uu >> 1, arr = uu & 1;
        unsigned K2 = gcnt[ss];
        unsigned kk2 = (unsigned)(int)floorf((float)K2 * 0.7f);
        Sel S;
        select_unit(h1c + uu * NBINS, kk2, sufB, bcast, S);
        if (S.b1 != 0xFFFFFFFFu) {
            // gather 64 private sub-hists: thread t owns sub-bin t
            float cc = 0.f, sm = 0.f;
            for (int c2 = 0; c2 < BPSAMP; ++c2) {
                const float* hp = hpriv + (size_t)(ss * BPSAMP + c2) * (4 * NBINS2) + arr * 2 * NBINS2;
                cc += hp[tid];
                sm += hp[NBINS2 + tid];
            }
            // total sum above b1
            sufF[tid] = (tid < BPSAMP) ? sgl[(size_t)(ss * BPSAMP + tid) * 2 + arr] : 0.f;
            __syncthreads();
            for (int off = TPB / 2; off > 0; off >>= 1) {
                if (tid < off) sufF[tid] += sufF[tid + off];
                __syncthreads();
            }
            float Ltot = sufF[0];
            __syncthreads();
            // joint suffix scans of counts and sums over 256 sub-bins
            unsigned myc = (unsigned)cc;
            sufB[tid] = myc; sufF[tid] = sm;
            __syncthreads();
            for (int off = 1; off < TPB; off <<= 1) {
                unsigned ac = (tid + off < TPB) ? sufB[tid + off] : 0u;
                float    as = (tid + off < TPB) ? sufF[tid + off] : 0.f;
                __syncthreads();
                sufB[tid] += ac; sufF[tid] += as;
                __syncthreads();
            }
            unsigned suf = sufB[tid];
            unsigned above = suf - myc;
            if (above < S.rem && S.rem <= suf) {   // exactly one thread
                unsigned rem2 = S.rem - above;
                float avg = sm / (float)myc;       // myc >= rem2 >= 1
                float sum_k = Ltot + (sufF[tid] - sm) + (float)rem2 * avg;
                float loss = sum_k / ((float)S.k + 1e-6f);
                atomicAdd(out, 0.0625f * loss);    // 0.5 stage weight / 8 samples, both arrays
            }
        }
    }
}

extern "C" void kernel_launch(void* const* d_in, const int* in_sizes, int n_in,
                              void* d_out, int out_size, void* d_ws, size_t ws_size,
                              hipStream_t stream)
{
    const float* image  = (const float*)d_in[0];
    const float* alpha  = (const float*)d_in[1];
    const float* pred   = (const float*)d_in[2];
    const int*   trimap = (const int*)d_in[3];
    const float* fg     = (const float*)d_in[4];
    const float* bg     = (const float*)d_in[5];
    float* out = (float*)d_out;

    char* ws = (char*)d_ws;
    // layout: bar 4KB (2 slots x 2KB, counters/flag on separate 64B lines) |
    //         gcnt[8] (64B) | h1c 64KB | sgl 4KB | pad | hpriv 2MB
    unsigned* bar   = (unsigned*)(ws);
    unsigned* gcnt  = (unsigned*)(ws + 4096);
    unsigned* h1c   = (unsigned*)(ws + 4096 + 64);
    float*    sgl   = (float*)(ws + 4096 + 64 + 65536);
    float*    hpriv = (float*)(ws + 131072);
    const size_t zbytes = 4096 + 64 + 65536;   // bar + gcnt + h1c (sgl/hpriv fully overwritten before read)

    hipMemsetAsync(d_ws, 0, zbytes, stream);
    hipMemsetAsync(d_out, 0, sizeof(float), stream);
    k_fused<<<NBLK, TPB, 0, stream>>>(image, alpha, pred, trimap, fg, bg,
                                      bar, gcnt, h1c, hpriv, sgl, out);
}

// Round 8
// 146.102 us; speedup vs baseline: 1.7252x; 1.7252x over previous
//
#include <hip/hip_runtime.h>
#include <math.h>

#define NB 8            // batch
#define NPIX 262144     // 512*512
#define TPB 256
#define BPS 64          // k1 blocks per sample
#define PPB (NPIX / BPS)    // 4096 pixels per block
#define NBINS 1024      // level-1 bins: bits>>21 of positive float < 2^128 -> < 1024
#define BPT (NBINS / TPB)   // 4
#define NBINS2 256      // level-2 sub-bins: (bits>>13)&255
#define BPU 32          // k2 blocks per unit
#define CPB (NPIX / BPU)    // 8192 values per k2 block
#define EPS2 1e-12f

#define F4E(v,j) (((const float*)&(v))[j])
#define I4E(v,j) (((const int*)&(v))[j])

struct Sel { unsigned b1, rem, k; };

__device__ __forceinline__ void pixel_vals(float a, float p,
                                           float i0, float i1, float i2,
                                           float f0, float f1, float f2,
                                           float g0, float g1, float g2,
                                           float& d, float& dc)
{
    float diff = a * (1.0f / 255.0f) - p;
    d = sqrtf(diff * diff + EPS2);
    float om = 1.0f - p;
    float e0 = i0 - (f0 * p + om * g0);
    float e1 = i1 - (f1 * p + om * g1);
    float e2 = i2 - (f2 * p + om * g2);
    dc = sqrtf(e0 * e0 + EPS2) + sqrtf(e1 * e1 + EPS2) + sqrtf(e2 * e2 + EPS2);
}

// Block-collective selection over a 1024-bin count histogram: find b1 with
// count(bin > b1) < k <= count(bin >= b1); rem = k - count(bin > b1).
// Masked pixels are excluded from the hist; their value (0.0f, bin 0) is
// always < any real value (>= 1e-6, bin ~428), so b1 > 0 and zeros never
// land in the sum-above or boundary bin.
__device__ void select_unit(const unsigned* __restrict__ hc, unsigned k,
                            unsigned* sufB, unsigned* bcast, Sel& out)
{
    const int t = threadIdx.x;
    unsigned bins[BPT];
    unsigned pc = 0;
#pragma unroll
    for (int j = 0; j < BPT; ++j) { bins[j] = hc[t * BPT + j]; pc += bins[j]; }
    sufB[t] = pc;
    __syncthreads();
    // inclusive suffix sum (Hillis-Steele; read-sync-write-sync)
    for (int off = 1; off < TPB; off <<= 1) {
        unsigned add = (t + off < TPB) ? sufB[t + off] : 0u;
        __syncthreads();
        sufB[t] += add;
        __syncthreads();
    }
    unsigned suf = sufB[t];
    if (t == 0) { bcast[0] = 0xFFFFFFFFu; bcast[1] = 0u; bcast[2] = 0u; }
    __syncthreads();
    if (k > 0) {
        unsigned above = suf - pc;
        if (above < k && k <= suf) {       // exactly one thread
            unsigned c = above; int b1 = -1;
#pragma unroll
            for (int j = BPT - 1; j >= 0; --j) {
                if (b1 < 0) {
                    if (c + bins[j] >= k) b1 = t * BPT + j;
                    else c += bins[j];
                }
            }
            bcast[0] = (unsigned)b1; bcast[1] = k - c; bcast[2] = k;
        }
    }
    __syncthreads();
    out.b1 = bcast[0]; out.rem = bcast[1]; out.k = bcast[2];
    __syncthreads();   // safe LDS reuse after return
}

// ------- k1: compute d/dc, write vals (0 for masked), LDS count hist, gcnt -------
__global__ __launch_bounds__(TPB) void k_pass1(
    const float* __restrict__ image, const float* __restrict__ alpha,
    const float* __restrict__ pred, const int* __restrict__ trimap,
    const float* __restrict__ fg, const float* __restrict__ bg,
    unsigned* __restrict__ gcnt, unsigned* __restrict__ h1c, float* __restrict__ vals)
{
    __shared__ unsigned hc[2 * NBINS];   // counts: [0..NBINS)=d, [NBINS..2N)=dc
    __shared__ unsigned wred[4];
    const int tid = threadIdx.x;
    for (int i = tid; i < 2 * NBINS; i += TPB) hc[i] = 0u;
    __syncthreads();

    const int s = blockIdx.x / BPS;
    const int chunk = blockIdx.x % BPS;
    const int pbase = s * NPIX + chunk * PPB;
    const int cbase = s * 3 * NPIX + chunk * PPB;
    float* vd = vals + (size_t)(s * 2 + 0) * NPIX + chunk * PPB;
    float* vc = vals + (size_t)(s * 2 + 1) * NPIX + chunk * PPB;

    unsigned nUnk = 0;
    for (int it = 0; it < PPB / (TPB * 4); ++it) {
        const int off = (it * TPB + tid) * 4;
        int4   tm = *(const int4*)(trimap + pbase + off);
        float4 al = *(const float4*)(alpha + pbase + off);
        float4 pr = *(const float4*)(pred + pbase + off);
        float4 i0 = *(const float4*)(image + cbase + off);
        float4 i1 = *(const float4*)(image + cbase + NPIX + off);
        float4 i2 = *(const float4*)(image + cbase + 2 * NPIX + off);
        float4 f0 = *(const float4*)(fg + cbase + off);
        float4 f1 = *(const float4*)(fg + cbase + NPIX + off);
        float4 f2 = *(const float4*)(fg + cbase + 2 * NPIX + off);
        float4 g0 = *(const float4*)(bg + cbase + off);
        float4 g1 = *(const float4*)(bg + cbase + NPIX + off);
        float4 g2 = *(const float4*)(bg + cbase + 2 * NPIX + off);
        float4 od, oc;
#pragma unroll
        for (int j = 0; j < 4; ++j) {
            float d = 0.f, c = 0.f;
            if (I4E(tm, j) == 128) {
                ++nUnk;
                pixel_vals(F4E(al, j), F4E(pr, j),
                           F4E(i0, j), F4E(i1, j), F4E(i2, j),
                           F4E(f0, j), F4E(f1, j), F4E(f2, j),
                           F4E(g0, j), F4E(g1, j), F4E(g2, j), d, c);
                atomicAdd(&hc[__float_as_uint(d) >> 21], 1u);
                atomicAdd(&hc[NBINS + (__float_as_uint(c) >> 21)], 1u);
            }
            ((float*)&od)[j] = d;
            ((float*)&oc)[j] = c;
        }
        *(float4*)(vd + off) = od;
        *(float4*)(vc + off) = oc;
    }

    unsigned u = nUnk;
#pragma unroll
    for (int o = 32; o > 0; o >>= 1) u += __shfl_down(u, o);
    if ((tid & 63) == 0) wred[tid >> 6] = u;
    __syncthreads();
    if (tid == 0) atomicAdd(&gcnt[s], wred[0] + wred[1] + wred[2] + wred[3]);

    for (int i = tid; i < 2 * NBINS; i += TPB) {
        unsigned cc = hc[i];
        if (cc) atomicAdd(&h1c[(s * 2 + (i >= NBINS ? 1 : 0)) * NBINS + (i & (NBINS - 1))], cc);
    }
}

// ------- k2: per-block selection (redundant), scan vals: sum>b1 + boundary LDS sub-hist -------
__global__ __launch_bounds__(TPB) void k_pass2(
    const float* __restrict__ vals, const unsigned* __restrict__ gcnt,
    const unsigned* __restrict__ h1c, float* __restrict__ hpriv,
    float* __restrict__ sumpart)
{
    __shared__ unsigned sufB[TPB];
    __shared__ unsigned bcast[4];
    __shared__ unsigned scnt[NBINS2];
    __shared__ float    ssum[NBINS2];
    __shared__ float    wred[4];
    const int tid = threadIdx.x;
    const int unit = blockIdx.x >> 5;       // BPU = 32
    const int chunk = blockIdx.x & (BPU - 1);
    const int s = unit >> 1;

    unsigned K = gcnt[s];
    unsigned kk = (unsigned)(int)floorf((float)K * 0.7f);
    Sel S;
    select_unit(h1c + unit * NBINS, kk, sufB, bcast, S);
    if (S.b1 == 0xFFFFFFFFu) return;        // k==0: unit contributes 0; k_final skips it too

    scnt[tid] = 0u; ssum[tid] = 0.f;        // TPB == NBINS2
    __syncthreads();

    const float* v = vals + (size_t)unit * NPIX + chunk * CPB;
    float lsum = 0.f;
#pragma unroll
    for (int it = 0; it < CPB / (TPB * 4); ++it) {
        const int off = (it * TPB + tid) * 4;
        float4 x = *(const float4*)(v + off);
#pragma unroll
        for (int j = 0; j < 4; ++j) {
            float val = F4E(x, j);
            unsigned bits = __float_as_uint(val);
            unsigned b = bits >> 21;
            if (b > S.b1) {
                lsum += val;
            } else if (b == S.b1) {
                unsigned sb = (bits >> 13) & (NBINS2 - 1);
                atomicAdd(&scnt[sb], 1u);
                atomicAdd(&ssum[sb], val);
            }
        }
    }
#pragma unroll
    for (int o = 32; o > 0; o >>= 1) lsum += __shfl_down(lsum, o);
    if ((tid & 63) == 0) wred[tid >> 6] = lsum;
    __syncthreads();                        // also orders sub-hist LDS atomics
    if (tid == 0)
        sumpart[unit * BPU + chunk] = wred[0] + wred[1] + wred[2] + wred[3];
    // private sub-hist flush (plain stores; coherence via kernel boundary)
    float* hp = hpriv + (size_t)(unit * BPU + chunk) * (2 * NBINS2);
    hp[tid] = (float)scnt[tid];
    hp[NBINS2 + tid] = ssum[tid];
}

// ------- k3: finalize (16 blocks, one per unit) -------
__global__ __launch_bounds__(TPB) void k_final(
    const unsigned* __restrict__ gcnt, const unsigned* __restrict__ h1c,
    const float* __restrict__ hpriv, const float* __restrict__ sumpart,
    float* __restrict__ out)
{
    __shared__ unsigned sufB[TPB];
    __shared__ unsigned bcast[4];
    __shared__ float    sufF[TPB];
    const int tid = threadIdx.x;
    const int unit = blockIdx.x;
    const int s = unit >> 1;

    unsigned K = gcnt[s];
    unsigned kk = (unsigned)(int)floorf((float)K * 0.7f);
    Sel S;
    select_unit(h1c + unit * NBINS, kk, sufB, bcast, S);
    if (S.b1 == 0xFFFFFFFFu) return;        // k==0 contributes 0

    // total sum above b1 (32 partials)
    sufF[tid] = (tid < BPU) ? sumpart[unit * BPU + tid] : 0.f;
    __syncthreads();
    for (int off = TPB / 2; off > 0; off >>= 1) {
        if (tid < off) sufF[tid] += sufF[tid + off];
        __syncthreads();
    }
    float Ltot = sufF[0];
    __syncthreads();

    // gather 32 private sub-hists: thread t owns sub-bin t
    float cc = 0.f, sm = 0.f;
    for (int c2 = 0; c2 < BPU; ++c2) {
        const float* hp = hpriv + (size_t)(unit * BPU + c2) * (2 * NBINS2);
        cc += hp[tid];
        sm += hp[NBINS2 + tid];
    }
    unsigned myc = (unsigned)cc;            // exact: integral floats <= 262144
    sufB[tid] = myc; sufF[tid] = sm;
    __syncthreads();
    for (int off = 1; off < TPB; off <<= 1) {
        unsigned ac = (tid + off < TPB) ? sufB[tid + off] : 0u;
        float    as = (tid + off < TPB) ? sufF[tid + off] : 0.f;
        __syncthreads();
        sufB[tid] += ac; sufF[tid] += as;
        __syncthreads();
    }
    unsigned suf = sufB[tid];
    unsigned above = suf - myc;
    if (above < S.rem && S.rem <= suf) {    // exactly one thread
        unsigned rem2 = S.rem - above;
        float avg = sm / (float)myc;        // myc >= rem2 >= 1
        float sum_k = Ltot + (sufF[tid] - sm) + (float)rem2 * avg;
        float loss = sum_k / ((float)S.k + 1e-6f);
        atomicAdd(out, 0.0625f * loss);     // 0.5 stage weight / 8 samples, both arrays
    }
}

extern "C" void kernel_launch(void* const* d_in, const int* in_sizes, int n_in,
                              void* d_out, int out_size, void* d_ws, size_t ws_size,
                              hipStream_t stream)
{
    const float* image  = (const float*)d_in[0];
    const float* alpha  = (const float*)d_in[1];
    const float* pred   = (const float*)d_in[2];
    const int*   trimap = (const int*)d_in[3];
    const float* fg     = (const float*)d_in[4];
    const float* bg     = (const float*)d_in[5];
    float* out = (float*)d_out;

    char* ws = (char*)d_ws;
    // layout: gcnt[8] 64B | h1c 64KB | sumpart 2KB | pad | hpriv 1MB | vals 16.8MB
    unsigned* gcnt    = (unsigned*)(ws);
    unsigned* h1c     = (unsigned*)(ws + 64);
    float*    sumpart = (float*)(ws + 64 + 65536);
    float*    hpriv   = (float*)(ws + 131072);
    float*    vals    = (float*)(ws + 131072 + 1048576);
    const size_t zbytes = 64 + 65536;   // gcnt + h1c (sumpart/hpriv/vals written before any read)

    hipMemsetAsync(d_ws, 0, zbytes, stream);
    hipMemsetAsync(d_out, 0, sizeof(float), stream);
    k_pass1<<<NB * BPS, TPB, 0, stream>>>(image, alpha, pred, trimap, fg, bg, gcnt, h1c, vals);
    k_pass2<<<NB * 2 * BPU, TPB, 0, stream>>>(vals, gcnt, h1c, hpriv, sumpart);
    k_final<<<NB * 2, TPB, 0, stream>>>(gcnt, h1c, hpriv, sumpart, out);
}

// Round 9
// 131.334 us; speedup vs baseline: 1.9192x; 1.1124x over previous
//
#include <hip/hip_runtime.h>
#include <math.h>

#define NB 8            // batch
#define NPIX 262144     // 512*512
#define TPB 256
#define BPS 128         // k1 blocks per sample
#define PPB (NPIX / BPS)    // 2048 pixels per block
#define NBF 768         // fine bins: (bits>>18)-3488 covers [2^-18, 4) w/ 5 mantissa bits; <2^-18 clamps to 0
#define ELO 3488        // (127-18)<<5
#define BPTF 3          // bins per thread in finalize (768 = 3*256)
#define EPS2 1e-12f

#define F4E(v,j) (((const float*)&(v))[j])
#define I4E(v,j) (((const int*)&(v))[j])

__device__ __forceinline__ void pixel_vals(float a, float p,
                                           float i0, float i1, float i2,
                                           float f0, float f1, float f2,
                                           float g0, float g1, float g2,
                                           float& d, float& dc)
{
    float diff = a * (1.0f / 255.0f) - p;
    d = sqrtf(diff * diff + EPS2);
    float om = 1.0f - p;
    float e0 = i0 - (f0 * p + om * g0);
    float e1 = i1 - (f1 * p + om * g1);
    float e2 = i2 - (f2 * p + om * g2);
    dc = sqrtf(e0 * e0 + EPS2) + sqrtf(e1 * e1 + EPS2) + sqrtf(e2 * e2 + EPS2);
}

__device__ __forceinline__ int fbin(float v)
{
    int e = (int)(__float_as_uint(v) >> 18) - ELO;   // exp + 5 mantissa bits
    return e < 0 ? 0 : e;                            // v < 4 guaranteed => e < NBF
}

// ------- k1: stream inputs, LDS count+sum fine histogram, flush to global -------
// Masked pixels excluded: their value (1e-6 / 3e-6) is <= any unknown value and
// k = floor(0.7*unknown) < unknown, so the top-k sum is unchanged (tie-safe) —
// validated by rounds 1/2/8 passing with this exclusion.
__global__ __launch_bounds__(TPB) void k_hist(
    const float* __restrict__ image, const float* __restrict__ alpha,
    const float* __restrict__ pred, const int* __restrict__ trimap,
    const float* __restrict__ fg, const float* __restrict__ bg,
    unsigned* __restrict__ h1c, float* __restrict__ h1s)
{
    __shared__ unsigned hcnt[2 * NBF];   // [0..NBF)=d, [NBF..2NBF)=dc
    __shared__ float    hsum[2 * NBF];
    const int tid = threadIdx.x;
    for (int i = tid; i < 2 * NBF; i += TPB) { hcnt[i] = 0u; hsum[i] = 0.f; }
    __syncthreads();

    const int s = blockIdx.x / BPS;
    const int chunk = blockIdx.x % BPS;
    const int pbase = s * NPIX + chunk * PPB;
    const int cbase = s * 3 * NPIX + chunk * PPB;

    for (int it = 0; it < PPB / (TPB * 4); ++it) {
        const int off = (it * TPB + tid) * 4;
        int4   tm = *(const int4*)(trimap + pbase + off);
        float4 al = *(const float4*)(alpha + pbase + off);
        float4 pr = *(const float4*)(pred + pbase + off);
        float4 i0 = *(const float4*)(image + cbase + off);
        float4 i1 = *(const float4*)(image + cbase + NPIX + off);
        float4 i2 = *(const float4*)(image + cbase + 2 * NPIX + off);
        float4 f0 = *(const float4*)(fg + cbase + off);
        float4 f1 = *(const float4*)(fg + cbase + NPIX + off);
        float4 f2 = *(const float4*)(fg + cbase + 2 * NPIX + off);
        float4 g0 = *(const float4*)(bg + cbase + off);
        float4 g1 = *(const float4*)(bg + cbase + NPIX + off);
        float4 g2 = *(const float4*)(bg + cbase + 2 * NPIX + off);
#pragma unroll
        for (int j = 0; j < 4; ++j) {
            if (I4E(tm, j) == 128) {
                float d, c;
                pixel_vals(F4E(al, j), F4E(pr, j),
                           F4E(i0, j), F4E(i1, j), F4E(i2, j),
                           F4E(f0, j), F4E(f1, j), F4E(f2, j),
                           F4E(g0, j), F4E(g1, j), F4E(g2, j), d, c);
                int bd = fbin(d), bc = fbin(c);
                atomicAdd(&hcnt[bd], 1u);       atomicAdd(&hsum[bd], d);
                atomicAdd(&hcnt[NBF + bc], 1u); atomicAdd(&hsum[NBF + bc], c);
            }
        }
    }
    __syncthreads();

    // flush nonzero bins (device-scope atomics; fine bins => low same-address contention)
    for (int i = tid; i < 2 * NBF; i += TPB) {
        unsigned cc = hcnt[i];
        if (cc) {
            int arr = (i >= NBF) ? 1 : 0;
            int b = i - arr * NBF;
            atomicAdd(&h1c[(s * 2 + arr) * NBF + b], cc);
            atomicAdd(&h1s[(s * 2 + arr) * NBF + b], hsum[i]);
        }
    }
}

// ------- k2: per-unit finalize from histograms alone (16 blocks) -------
__global__ __launch_bounds__(TPB) void k_final(
    const unsigned* __restrict__ h1c, const float* __restrict__ h1s,
    float* __restrict__ out)
{
    __shared__ unsigned sufB[TPB];
    __shared__ float    sufF[TPB];
    __shared__ unsigned kbc[1];
    const int t = threadIdx.x;
    const int unit = blockIdx.x;

    unsigned cnt[BPTF]; float sm[BPTF];
    unsigned pc = 0; float ps = 0.f;
#pragma unroll
    for (int j = 0; j < BPTF; ++j) {
        cnt[j] = h1c[unit * NBF + t * BPTF + j];
        sm[j]  = h1s[unit * NBF + t * BPTF + j];
        pc += cnt[j]; ps += sm[j];
    }
    sufB[t] = pc; sufF[t] = ps;
    __syncthreads();
    // joint inclusive suffix scans (Hillis-Steele; read-sync-write-sync)
    for (int off = 1; off < TPB; off <<= 1) {
        unsigned ac = (t + off < TPB) ? sufB[t + off] : 0u;
        float    as = (t + off < TPB) ? sufF[t + off] : 0.f;
        __syncthreads();
        sufB[t] += ac; sufF[t] += as;
        __syncthreads();
    }
    if (t == 0) kbc[0] = sufB[0];          // K = total unknown count (all values in hist)
    __syncthreads();
    unsigned K = kbc[0];
    unsigned kk = (unsigned)(int)floorf((float)K * 0.7f);
    if (kk == 0) return;                   // unit contributes 0 (out pre-zeroed)

    unsigned suf = sufB[t];
    unsigned above = suf - pc;             // count in bins above this thread's range
    if (above < kk && kk <= suf) {         // exactly one thread
        unsigned c = above;
        float sa = sufF[t] - ps;           // sum in bins above this thread's range
        int done = 0;
#pragma unroll
        for (int j = BPTF - 1; j >= 0; --j) {   // descending bin value
            if (!done) {
                if (c + cnt[j] >= kk) {
                    unsigned rem = kk - c;               // 1 <= rem <= cnt[j]
                    float avg = sm[j] / (float)cnt[j];   // bin width 2^-5 rel; error ~0.03% of sum_k
                    float sum_k = sa + (float)rem * avg;
                    float loss = sum_k / ((float)kk + 1e-6f);
                    atomicAdd(out, 0.0625f * loss);      // 0.5 stage weight / 8 samples, both arrays
                    done = 1;
                } else {
                    c += cnt[j]; sa += sm[j];
                }
            }
        }
    }
}

extern "C" void kernel_launch(void* const* d_in, const int* in_sizes, int n_in,
                              void* d_out, int out_size, void* d_ws, size_t ws_size,
                              hipStream_t stream)
{
    const float* image  = (const float*)d_in[0];
    const float* alpha  = (const float*)d_in[1];
    const float* pred   = (const float*)d_in[2];
    const int*   trimap = (const int*)d_in[3];
    const float* fg     = (const float*)d_in[4];
    const float* bg     = (const float*)d_in[5];
    float* out = (float*)d_out;

    char* ws = (char*)d_ws;
    // layout: h1c 16*768*4 = 48KB | h1s 48KB
    unsigned* h1c = (unsigned*)(ws);
    float*    h1s = (float*)(ws + 16 * NBF * 4);
    const size_t zbytes = 2 * 16 * NBF * 4;   // both hists (float 0.0 == all-zero bits)

    hipMemsetAsync(d_ws, 0, zbytes, stream);
    hipMemsetAsync(d_out, 0, sizeof(float), stream);
    k_hist<<<NB * BPS, TPB, 0, stream>>>(image, alpha, pred, trimap, fg, bg, h1c, h1s);
    k_final<<<NB * 2, TPB, 0, stream>>>(h1c, h1s, out);
}